// Round 16
// baseline (280.374 us; speedup 1.0000x reference)
//
#include <hip/hip_runtime.h>

typedef unsigned short u16;
typedef unsigned int   u32;
typedef short bf16x8 __attribute__((ext_vector_type(8)));
typedef float f32x16 __attribute__((ext_vector_type(16)));

#define NB    8
#define NP    3136
#define DIM   256
#define PTILE 16
#define NEGM  (-100.0f)
#define QKSCALE 0.17677669529663687f

// LDS 52K, time-multiplexed (every write lands in a provably-dead hole):
//  staging: A0h @0-16K
//  s0 GEMM1: reads A0; scatter Q0 @16-32K, K0 @32-48K
//  dots0: reads Q0/K0; p0 @0-8K (A0 dead)
//  PV0: reads p0; writes A1h @16-48K (Q0/K0 dead)
//  s1 Qpass: reads A1h; scatter Q1 @0-16K (p0 dead)
//  s1 K/V passes -> regs; barrier; K1 scatter @16-48K (A1h dead)
//  dots1: reads Q1 @0-16K, K1 @16-48K; p1 @48-52K
//  PV1: reads p1; attnout1 hi @0-16K, lo @16-32K (Q1/K1 dead)
//  GEMM2: reads hi/lo.
#define LDS_SZ  53248
#define Q0B     16384
#define K0B     32768
#define A1B     16384
#define K1B     16384
#define P1B     49152
#define AO1LB   16384

__device__ __forceinline__ float bflo(u32 w) { return __uint_as_float(w << 16); }
__device__ __forceinline__ float bfhi(u32 w) { return __uint_as_float(w & 0xffff0000u); }

__device__ __forceinline__ u32 cvt_pk(float a, float b) {
  u32 r;
  asm("v_cvt_pk_bf16_f32 %0, %1, %2" : "=v"(r) : "v"(a), "v"(b));
  return r;
}

__device__ __forceinline__ void phase_fence() { __builtin_amdgcn_sched_barrier(0); }

template<int MASKI>
__device__ __forceinline__ float maskv(int i, int j) {
  if (MASKI == 0) return ((i ^ j) == 3) ? NEGM : 0.f;
  return (i >= 2 || ((i ^ j) & 1)) ? NEGM : 0.f;
}

#define FRAG(nt, ks) ((((size_t)(nt) * 16 + (ks)) * 64 + lane) * 8)

// ---------------- prologue kernels ----------------
__device__ __forceinline__ void pack4(const float* __restrict__ W,
                                      u16* __restrict__ hi, u16* __restrict__ lo,
                                      int is_qkv, int pair0, int tid) {
  const int p    = pair0 + (tid >> 6);
  const int lane = tid & 63;
  const int nt = p >> 4, ks = p & 15;
  const int n  = nt * 32 + (lane & 31);
  const int k0 = ks * 16 + ((lane >> 5) << 3);
  const float scale = (is_qkv && n < 256) ? QKSCALE : 1.0f;
  const float* src = W + (size_t)n * 256 + k0;
  const size_t o = (((size_t)nt * 16 + ks) * 64 + lane) * 8;
#pragma unroll
  for (int j = 0; j < 8; j++) {
    float v = src[j] * scale;
    u32 wh = cvt_pk(v, v);
    hi[o + j] = (u16)wh;
    if (lo) lo[o + j] = (u16)cvt_pk(v - bflo(wh), 0.f);
  }
}

// blocks: [0,1568) mean partials; [1568,1664) pack wqkv0; [1664,1696) pack
// wout1; [1696,1720) Wc strip combo+pack (self-contained, no global Wc);
// [1720,1723) combo_b.
__global__ __launch_bounds__(256)
void prep1(const float* __restrict__ x, const float* __restrict__ y,
           float* __restrict__ part,
           const float* __restrict__ wqkv0, u16* __restrict__ wq0_hi,
           const float* __restrict__ wout1, u16* __restrict__ wo1_hi, u16* __restrict__ wo1_lo,
           const float* __restrict__ wqkv1, const float* __restrict__ wout0,
           u16* __restrict__ wc_hi, u16* __restrict__ wc_lo,
           const float* __restrict__ bout0, float* __restrict__ bq) {
  __shared__ float smem[32 * 256];
  const int bid = blockIdx.x;
  const int tid = threadIdx.x;
  if (bid < 1568) {                      // mean partials (98 chunks x 16 ab)
    const int ab = bid / 98;
    const int chunk = bid - ab * 98;
    const int b = ab & 7;
    const float* src = (ab >> 3) ? y : x;
    float s = 0.f;
    const int p0 = chunk * 32;           // 3136 = 98*32
#pragma unroll 4
    for (int i = 0; i < 32; i++)
      s += src[((size_t)b * NP + p0 + i) * DIM + tid];
    part[((size_t)ab * 98 + chunk) * DIM + tid] = s;
  } else if (bid < 1664) {               // pack wqkv0 hi-only (384 pairs)
    pack4(wqkv0, wq0_hi, nullptr, 1, (bid - 1568) * 4, tid);
  } else if (bid < 1696) {               // pack wout1 hi+lo (128 pairs)
    pack4(wout1, wo1_hi, wo1_lo, 0, (bid - 1664) * 4, tid);
  } else if (bid < 1720) {               // Wc strip nt: compute + pack
    const int nt = bid - 1696;
#pragma unroll 4
    for (int r = 0; r < 32; r++)
      smem[r * 256 + tid] = wqkv1[(size_t)(nt * 32 + r) * 256 + tid];
    __syncthreads();
    float acc[32];
#pragma unroll
    for (int n = 0; n < 32; n++) acc[n] = 0.f;
    for (int d = 0; d < 256; d++) {
      const float w0 = wout0[(size_t)d * 256 + tid];
#pragma unroll
      for (int n = 0; n < 32; n++) acc[n] += smem[n * 256 + d] * w0;
    }
    __syncthreads();
    const float scale = (nt < 8) ? QKSCALE : 1.0f;
#pragma unroll
    for (int n = 0; n < 32; n++) smem[n * 256 + tid] = acc[n] * scale;
    __syncthreads();
    const int lane = tid & 63;
#pragma unroll 1
    for (int pass = 0; pass < 4; pass++) {
      const int ks = pass * 4 + (tid >> 6);
      const int nl = lane & 31;
      const int k0 = ks * 16 + ((lane >> 5) << 3);
      const size_t o = (((size_t)nt * 16 + ks) * 64 + lane) * 8;
#pragma unroll
      for (int j = 0; j < 8; j++) {
        float v = smem[nl * 256 + k0 + j];
        u32 wh = cvt_pk(v, v);
        wc_hi[o + j] = (u16)wh;
        wc_lo[o + j] = (u16)cvt_pk(v - bflo(wh), 0.f);
      }
    }
  } else {                               // bq = Wqkv1 . bout0 (Q rows scaled)
    const int n = (bid - 1720) * 256 + tid;
    float s = 0.f;
    for (int d = 0; d < 256; d += 4) {
      const float4 w = *(const float4*)(wqkv1 + (size_t)n * 256 + d);
      const float4 bv = *(const float4*)(bout0 + d);
      s += w.x * bv.x + w.y * bv.y + w.z * bv.z + w.w * bv.w;
    }
    bq[n] = (n < 256) ? s * QKSCALE : s;
  }
}

// 16 blocks: mean_final + qkvg (g stays in smem, never hits HBM).
__global__ __launch_bounds__(256)
void prep2(const float* __restrict__ part, const float* __restrict__ wqkv0,
           float* __restrict__ qkvg) {
  __shared__ float srow[256];
  const int bid = blockIdx.x;
  const int tid = threadIdx.x;
  float s = 0.f;
  for (int c = 0; c < 98; c++) s += part[((size_t)bid * 98 + c) * DIM + tid];
  srow[tid] = s * (1.0f / 3136.0f);
  __syncthreads();
  const int bt = (bid < 8) ? (2 * bid) : (2 * (bid - 8) + 1);
#pragma unroll
  for (int sct = 0; sct < 3; sct++) {
    const int e = sct * 256 + tid;
    float acc = 0.f;
    for (int d = 0; d < 256; d += 4) {
      const float4 w = *(const float4*)(wqkv0 + (size_t)e * 256 + d);
      acc += w.x * srow[d] + w.y * srow[d + 1] + w.z * srow[d + 2] + w.w * srow[d + 3];
    }
    qkvg[(size_t)bt * 768 + e] = (e < 256) ? acc * QKSCALE : acc;
  }
}

// ---------------- fused double-stage kernel ----------------
__global__ __launch_bounds__(512, 6)
void fused_kernel(const float* __restrict__ x, const float* __restrict__ y,
                  const float* __restrict__ qkvg, float* __restrict__ outp,
                  const u16* __restrict__ wq0_hi,
                  const u16* __restrict__ wc_hi,  const u16* __restrict__ wc_lo,
                  const u16* __restrict__ wo1_hi, const u16* __restrict__ wo1_lo,
                  const float* __restrict__ bq,   const float* __restrict__ bout1) {
  extern __shared__ char lds[];
  const int tid  = threadIdx.x;
  const int lane = tid & 63;
  const int wave = tid >> 6;         // 0..7
  const int cl   = lane & 31;
  const int rh5  = lane >> 5;        // 0/1
  const int kgrp = rh5 << 3;
  const int b    = blockIdx.y;
  const int pos0 = blockIdx.x * PTILE;
  // attention role
  const int apos = wave * 2 + rh5;   // 0..15
  const int ah   = (lane >> 2) & 7;  // head
  const int adq  = lane & 3;         // 8 dims each
  const float* qg = qkvg + (size_t)(b * 2) * 768;

  // ---- stage A0 (32 rows = 16pos x {x,y}) bf16-hi only @0..16K ----
  {
    const int r   = tid >> 4;          // 0..31
    const int cb  = (tid & 15) * 16;
    const int pos = pos0 + (r >> 1);
    const float* src = ((r & 1) ? y : x) + ((size_t)b * NP + pos) * DIM;
#pragma unroll
    for (int u = 0; u < 4; u++) {
      const int col = cb + u * 4;
      float4 v = *(const float4*)(src + col);
      uint2 hw;
      hw.x = cvt_pk(v.x, v.y);
      hw.y = cvt_pk(v.z, v.w);
      *(uint2*)(lds + ((r * 512 + col * 2) ^ ((r & 15) << 4))) = hw;
    }
  }
  __syncthreads();
  phase_fence();

  // ================= STAGE 0 =================
  f32x16 av;
  {
    f32x16 aq, ak;
#pragma unroll
    for (int i = 0; i < 16; i++) { aq[i] = 0.f; ak[i] = 0.f; av[i] = 0.f; }
#pragma unroll 2
    for (int ks = 0; ks < 16; ks++) {
      const int k0 = ks * 16 + kgrp;
      bf16x8 ahf = *(const bf16x8*)(lds + ((cl * 512 + k0 * 2) ^ ((cl & 15) << 4)));
      bf16x8 bQ = *(const bf16x8*)(wq0_hi + FRAG(wave, ks));
      bf16x8 bK = *(const bf16x8*)(wq0_hi + FRAG(8 + wave, ks));
      bf16x8 bV = *(const bf16x8*)(wq0_hi + FRAG(16 + wave, ks));
      __builtin_amdgcn_s_setprio(1);
      aq = __builtin_amdgcn_mfma_f32_32x32x16_bf16(ahf, bQ, aq, 0, 0, 0);
      ak = __builtin_amdgcn_mfma_f32_32x32x16_bf16(ahf, bK, ak, 0, 0, 0);
      av = __builtin_amdgcn_mfma_f32_32x32x16_bf16(ahf, bV, av, 0, 0, 0);
      __builtin_amdgcn_s_setprio(0);
    }
    // scatter Q0 @16-32K / K0 @32-48K col-major [h=wave][d=cl][p2]
    const int sw0 = ((cl ^ wave) & 7) << 3;
    const int bQd = Q0B + wave * 2048 + cl * 64;
    const int bKd = K0B + wave * 2048 + cl * 64;
#pragma unroll
    for (int gq = 0; gq < 4; gq++) {
      const int p20 = 8 * gq + 4 * rh5;
      uint2 wv;
      wv.x = cvt_pk(aq[4 * gq + 0], aq[4 * gq + 1]);
      wv.y = cvt_pk(aq[4 * gq + 2], aq[4 * gq + 3]);
      *(uint2*)(lds + bQd + ((p20 * 2) ^ sw0)) = wv;
      wv.x = cvt_pk(ak[4 * gq + 0], ak[4 * gq + 1]);
      wv.y = cvt_pk(ak[4 * gq + 2], ak[4 * gq + 3]);
      *(uint2*)(lds + bKd + ((p20 * 2) ^ sw0)) = wv;
    }
  }
  __syncthreads();   // Q0/K0 visible; A0 dead
  phase_fence();

  // ---- dots0: p0 -> @0-8K (A0 dead) ----
  {
    const int e0 = ah * 32 + adq * 8;
    float dots[4][4];
#pragma unroll
    for (int i = 0; i < 4; i++)
#pragma unroll
      for (int j = 0; j < 4; j++) dots[i][j] = 0.f;
#pragma unroll 2
    for (int dd = 0; dd < 8; dd++) {
      const int d = adq * 8 + dd;
      const int sw = ((d ^ ah) & 7) << 3;
      u32 qw = *(const u32*)(lds + Q0B + ah * 2048 + d * 64 + ((apos * 4) ^ sw));
      u32 kw = *(const u32*)(lds + K0B + ah * 2048 + d * 64 + ((apos * 4) ^ sw));
      float q[4] = { bflo(qw), bfhi(qw), qg[e0 + dd], qg[768 + e0 + dd] };
      float k[4] = { bflo(kw), bfhi(kw), qg[256 + e0 + dd], qg[1024 + e0 + dd] };
#pragma unroll
      for (int i = 0; i < 4; i++)
#pragma unroll
        for (int j = 0; j < 4; j++) dots[i][j] += q[i] * k[j];
    }
#pragma unroll
    for (int i = 0; i < 4; i++)
#pragma unroll
      for (int j = 0; j < 4; j++) {
        float s = dots[i][j];
        s += __shfl_xor(s, 1);
        s += __shfl_xor(s, 2);
        dots[i][j] = s + maskv<0>(i, j);
      }
    if (adq == 0) {
#pragma unroll
      for (int i = 0; i < 4; i++) {
        const float mx = fmaxf(fmaxf(dots[i][0], dots[i][1]), fmaxf(dots[i][2], dots[i][3]));
        const float e0_ = __expf(dots[i][0] - mx), e1_ = __expf(dots[i][1] - mx);
        const float e2_ = __expf(dots[i][2] - mx), e3_ = __expf(dots[i][3] - mx);
        const float inv = 1.f / (e0_ + e1_ + e2_ + e3_);
        float4 pv_ = { e0_ * inv, e1_ * inv, e2_ * inv, e3_ * inv };
        *(float4*)(lds + ((apos * 8 + ah) * 4 + i) * 16) = pv_;
      }
    }
  }
  __syncthreads();   // p0 visible; Q0/K0 reads done
  phase_fence();

  // ---- PV0 + attnout0 write: A1h bf16 @16-48K (Q0/K0 dead); p0 @0-8K ----
  {
    const float vg2 = qg[512 + wave * 32 + cl];
    const float vg3 = qg[768 + 512 + wave * 32 + cl];
    const int c = wave * 32 + cl;
#pragma unroll
    for (int gq = 0; gq < 4; gq++) {
#pragma unroll
      for (int pp = 0; pp < 2; pp++) {
        const int pos = 4 * gq + 2 * rh5 + pp;
        const float v0 = av[4 * gq + 2 * pp], v1 = av[4 * gq + 2 * pp + 1];
#pragma unroll
        for (int i = 0; i < 4; i++) {
          float4 pi = *(const float4*)(lds + ((pos * 8 + wave) * 4 + i) * 16);
          const float o = pi.x * v0 + pi.y * v1 + pi.z * vg2 + pi.w * vg3;
          const int R = pos * 4 + i;
          *(u16*)(lds + A1B + ((R * 512 + c * 2) ^ ((R & 15) << 4))) = (u16)cvt_pk(o, o);
        }
      }
    }
  }
  __syncthreads();   // A1 visible; p0 reads done
  phase_fence();

  // ================= STAGE 1 (A = A1h @16-48K) =================
  // Q pass (2-pass), scatter Q1 @0-16K (p0 dead)
  {
    f32x16 aq0, aq1;
#pragma unroll
    for (int i = 0; i < 16; i++) { aq0[i] = 0.f; aq1[i] = 0.f; }
#pragma unroll 1
    for (int ks = 0; ks < 16; ks++) {
      const int k0 = ks * 16 + kgrp;
      bf16x8 ah0 = *(const bf16x8*)(lds + A1B + ((cl * 512 + k0 * 2) ^ ((cl & 15) << 4)));
      bf16x8 ah1 = *(const bf16x8*)(lds + A1B + (((32 + cl) * 512 + k0 * 2) ^ (((32 + cl) & 15) << 4)));
      bf16x8 bh = *(const bf16x8*)(wc_hi + FRAG(wave, ks));
      bf16x8 bl = *(const bf16x8*)(wc_lo + FRAG(wave, ks));
      __builtin_amdgcn_s_setprio(1);
      aq0 = __builtin_amdgcn_mfma_f32_32x32x16_bf16(ah0, bh, aq0, 0, 0, 0);
      aq0 = __builtin_amdgcn_mfma_f32_32x32x16_bf16(ah0, bl, aq0, 0, 0, 0);
      aq1 = __builtin_amdgcn_mfma_f32_32x32x16_bf16(ah1, bh, aq1, 0, 0, 0);
      aq1 = __builtin_amdgcn_mfma_f32_32x32x16_bf16(ah1, bl, aq1, 0, 0, 0);
      __builtin_amdgcn_s_setprio(0);
    }
    const float qb = bq[wave * 32 + cl];
    const int swq = ((cl ^ wave) & 7) << 3;
    const int bQ1 = wave * 2048 + cl * 64;   // @0-16K
#pragma unroll
    for (int gq = 0; gq < 4; gq++) {
      const int posA = 2 * gq + rh5;
      *(u32*)(lds + bQ1 + ((posA * 4) ^ swq)) =
          cvt_pk(aq0[4 * gq] + qb, aq0[4 * gq + 1] + qb);
      *(u32*)(lds + bQ1 + (((posA + 8) * 4) ^ swq)) =
          cvt_pk(aq1[4 * gq] + qb, aq1[4 * gq + 1] + qb);
    }
  }
  phase_fence();
  // K pass: accumulate, then PACK to bf16 u32 regs
  uint2 kp0[4], kp1[4];
  {
    f32x16 ak0, ak1;
#pragma unroll
    for (int i = 0; i < 16; i++) { ak0[i] = 0.f; ak1[i] = 0.f; }
#pragma unroll 1
    for (int ks = 0; ks < 16; ks++) {
      const int k0 = ks * 16 + kgrp;
      bf16x8 ah0 = *(const bf16x8*)(lds + A1B + ((cl * 512 + k0 * 2) ^ ((cl & 15) << 4)));
      bf16x8 ah1 = *(const bf16x8*)(lds + A1B + (((32 + cl) * 512 + k0 * 2) ^ (((32 + cl) & 15) << 4)));
      bf16x8 bh = *(const bf16x8*)(wc_hi + FRAG(8 + wave, ks));
      bf16x8 bl = *(const bf16x8*)(wc_lo + FRAG(8 + wave, ks));
      __builtin_amdgcn_s_setprio(1);
      ak0 = __builtin_amdgcn_mfma_f32_32x32x16_bf16(ah0, bh, ak0, 0, 0, 0);
      ak0 = __builtin_amdgcn_mfma_f32_32x32x16_bf16(ah0, bl, ak0, 0, 0, 0);
      ak1 = __builtin_amdgcn_mfma_f32_32x32x16_bf16(ah1, bh, ak1, 0, 0, 0);
      ak1 = __builtin_amdgcn_mfma_f32_32x32x16_bf16(ah1, bl, ak1, 0, 0, 0);
      __builtin_amdgcn_s_setprio(0);
    }
    const float kb = bq[256 + wave * 32 + cl];
#pragma unroll
    for (int gq = 0; gq < 4; gq++) {
      kp0[gq].x = cvt_pk(ak0[4 * gq + 0] + kb, ak0[4 * gq + 1] + kb);
      kp0[gq].y = cvt_pk(ak0[4 * gq + 2] + kb, ak0[4 * gq + 3] + kb);
      kp1[gq].x = cvt_pk(ak1[4 * gq + 0] + kb, ak1[4 * gq + 1] + kb);
      kp1[gq].y = cvt_pk(ak1[4 * gq + 2] + kb, ak1[4 * gq + 3] + kb);
    }
  }
  phase_fence();
  // V pass: 2-pass bf16
  f32x16 av0, av1;
  {
#pragma unroll
    for (int i = 0; i < 16; i++) { av0[i] = 0.f; av1[i] = 0.f; }
#pragma unroll 1
    for (int ks = 0; ks < 16; ks++) {
      const int k0 = ks * 16 + kgrp;
      bf16x8 ah0 = *(const bf16x8*)(lds + A1B + ((cl * 512 + k0 * 2) ^ ((cl & 15) << 4)));
      bf16x8 ah1 = *(const bf16x8*)(lds + A1B + (((32 + cl) * 512 + k0 * 2) ^ (((32 + cl) & 15) << 4)));
      bf16x8 bh = *(const bf16x8*)(wc_hi + FRAG(16 + wave, ks));
      bf16x8 bl = *(const bf16x8*)(wc_lo + FRAG(16 + wave, ks));
      __builtin_amdgcn_s_setprio(1);
      av0 = __builtin_amdgcn_mfma_f32_32x32x16_bf16(ah0, bh, av0, 0, 0, 0);
      av0 = __builtin_amdgcn_mfma_f32_32x32x16_bf16(ah0, bl, av0, 0, 0, 0);
      av1 = __builtin_amdgcn_mfma_f32_32x32x16_bf16(ah1, bh, av1, 0, 0, 0);
      av1 = __builtin_amdgcn_mfma_f32_32x32x16_bf16(ah1, bl, av1, 0, 0, 0);
      __builtin_amdgcn_s_setprio(0);
    }
    const float vb = bq[512 + wave * 32 + cl];
#pragma unroll
    for (int i = 0; i < 16; i++) { av0[i] += vb; av1[i] += vb; }
  }
  __syncthreads();   // A1 dead; Q1 visible
  phase_fence();

  // ---- scatter K1 [h][d][p4=64] @16-48K from packed regs ----
  {
    const int swk = ((cl ^ wave) & 7) << 4;
    const int bK1 = K1B + wave * 4096 + cl * 128;
#pragma unroll
    for (int gq = 0; gq < 4; gq++) {
      const int R0a = 8 * gq + 4 * rh5;
      *(uint2*)(lds + bK1 + ((R0a * 2) ^ swk)) = kp0[gq];
      *(uint2*)(lds + bK1 + (((R0a + 32) * 2) ^ swk)) = kp1[gq];
    }
  }
  __syncthreads();   // K1 visible
  phase_fence();

  // ---- dots1: Q1 @0-16K, K1 @16-48K; p1 @48-52K ----
  {
    float dots[2][4];
#pragma unroll
    for (int i = 0; i < 2; i++)
#pragma unroll
      for (int j = 0; j < 4; j++) dots[i][j] = 0.f;
#pragma unroll 2
    for (int dd = 0; dd < 8; dd++) {
      const int d = adq * 8 + dd;
      u32 qw = *(const u32*)(lds + ah * 2048 + d * 64 +
                             ((apos * 4) ^ (((d ^ ah) & 7) << 3)));
      uint2 kw = *(const uint2*)(lds + K1B + ah * 4096 + d * 128 +
                                 ((apos * 8) ^ (((d ^ ah) & 7) << 4)));
      float q[2] = { bflo(qw), bfhi(qw) };
      float k[4] = { bflo(kw.x), bfhi(kw.x), bflo(kw.y), bfhi(kw.y) };
#pragma unroll
      for (int i = 0; i < 2; i++)
#pragma unroll
        for (int j = 0; j < 4; j++) dots[i][j] += q[i] * k[j];
    }
#pragma unroll
    for (int i = 0; i < 2; i++)
#pragma unroll
      for (int j = 0; j < 4; j++) {
        float s = dots[i][j];
        s += __shfl_xor(s, 1);
        s += __shfl_xor(s, 2);
        dots[i][j] = s + maskv<1>(i, j);
      }
    if (adq == 0) {
#pragma unroll
      for (int i = 0; i < 2; i++) {
        const float mx = fmaxf(fmaxf(dots[i][0], dots[i][1]), fmaxf(dots[i][2], dots[i][3]));
        const float e0_ = __expf(dots[i][0] - mx), e1_ = __expf(dots[i][1] - mx);
        const float e2_ = __expf(dots[i][2] - mx), e3_ = __expf(dots[i][3] - mx);
        const float inv = 1.f / (e0_ + e1_ + e2_ + e3_);
        float4 pv_ = { e0_ * inv, e1_ * inv, e2_ * inv, e3_ * inv };
        *(float4*)(lds + P1B + ((apos * 8 + ah) * 2 + i) * 16) = pv_;
      }
    }
  }
  __syncthreads();   // p1 visible; Q1/K1 reads done
  phase_fence();

  // ---- PV1 + attnout1 write (hi @0-16K, lo @16-32K; p1 @48-52K) ----
  {
    const int c = wave * 32 + cl;
#pragma unroll
    for (int gq = 0; gq < 4; gq++) {
      const int posA = 2 * gq + rh5;
#pragma unroll
      for (int i = 0; i < 2; i++) {
        float4 pa = *(const float4*)(lds + P1B + ((posA * 8 + wave) * 2 + i) * 16);
        const float o0 = pa.x * av0[4 * gq] + pa.y * av0[4 * gq + 1] +
                         pa.z * av0[4 * gq + 2] + pa.w * av0[4 * gq + 3];
        const int r0 = posA * 2 + i;
        const u32 h0 = cvt_pk(o0, o0);
        const int bo0 = (r0 * 512 + c * 2) ^ ((r0 & 15) << 4);
        *(u16*)(lds + bo0) = (u16)h0;
        *(u16*)(lds + AO1LB + bo0) = (u16)cvt_pk(o0 - bflo(h0), 0.f);
        float4 pb = *(const float4*)(lds + P1B + (((posA + 8) * 8 + wave) * 2 + i) * 16);
        const float o1 = pb.x * av1[4 * gq] + pb.y * av1[4 * gq + 1] +
                         pb.z * av1[4 * gq + 2] + pb.w * av1[4 * gq + 3];
        const int r1 = (posA + 8) * 2 + i;
        const u32 h1 = cvt_pk(o1, o1);
        const int bo1 = (r1 * 512 + c * 2) ^ ((r1 & 15) << 4);
        *(u16*)(lds + bo1) = (u16)h1;
        *(u16*)(lds + AO1LB + bo1) = (u16)cvt_pk(o1 - bflo(h1), 0.f);
      }
    }
  }
  __syncthreads();   // attnout1 visible; p1 reads done
  phase_fence();

  // ---- GEMM2 (3-pass) + epilogue ----
  {
    f32x16 acc2;
#pragma unroll
    for (int i = 0; i < 16; i++) acc2[i] = 0.f;
#pragma unroll 2
    for (int ks = 0; ks < 16; ks++) {
      const int k0 = ks * 16 + kgrp;
      const int bo = (cl * 512 + k0 * 2) ^ ((cl & 15) << 4);
      bf16x8 ahf = *(const bf16x8*)(lds + bo);
      bf16x8 alf = *(const bf16x8*)(lds + AO1LB + bo);
      bf16x8 bh = *(const bf16x8*)(wo1_hi + FRAG(wave, ks));
      bf16x8 bl = *(const bf16x8*)(wo1_lo + FRAG(wave, ks));
      __builtin_amdgcn_s_setprio(1);
      acc2 = __builtin_amdgcn_mfma_f32_32x32x16_bf16(ahf, bh, acc2, 0, 0, 0);
      acc2 = __builtin_amdgcn_mfma_f32_32x32x16_bf16(ahf, bl, acc2, 0, 0, 0);
      acc2 = __builtin_amdgcn_mfma_f32_32x32x16_bf16(alf, bh, acc2, 0, 0, 0);
      __builtin_amdgcn_s_setprio(0);
    }
    const int c = wave * 32 + cl;
    const float bc = bout1[c];
    const size_t TOT = (size_t)NB * NP * DIM;
#pragma unroll
    for (int i = 0; i < 16; i++) {
      const int r = (i & 3) + ((i >> 2) << 3) + 4 * rh5;
      const int pos = pos0 + (r >> 1);
      const float v = acc2[i] + bc;
      if ((r & 1) == 0) outp[((size_t)b * NP + pos) * DIM + c] = v;
      else              outp[TOT + ((size_t)b * NP + pos) * DIM + c] = v;
    }
  }
}

extern "C" void kernel_launch(void* const* d_in, const int* in_sizes, int n_in,
                              void* d_out, int out_size, void* d_ws, size_t ws_size,
                              hipStream_t stream) {
  const float* x     = (const float*)d_in[0];
  const float* y     = (const float*)d_in[1];
  const float* wqkv0 = (const float*)d_in[2];
  const float* wout0 = (const float*)d_in[3];
  const float* bout0 = (const float*)d_in[4];
  const float* wqkv1 = (const float*)d_in[5];
  const float* wout1 = (const float*)d_in[6];
  const float* bout1 = (const float*)d_in[7];

  float* part = (float*)d_ws;                        // 16*98*256
  float* bq   = part + (size_t)16 * 98 * DIM;        // 768
  float* qkvg = bq + 768;                            // 8*2*768
  u16* w = (u16*)(qkvg + (size_t)8 * 2 * 768);
  u16* wq0_hi = w; w += (size_t)768 * 256;
  u16* wc_hi  = w; w += (size_t)768 * 256;
  u16* wc_lo  = w; w += (size_t)768 * 256;
  u16* wo1_hi = w; w += (size_t)256 * 256;
  u16* wo1_lo = w; w += (size_t)256 * 256;

  prep1<<<dim3(1723), dim3(256), 0, stream>>>(
      x, y, part, wqkv0, wq0_hi, wout1, wo1_hi, wo1_lo,
      wqkv1, wout0, wc_hi, wc_lo, bout0, bq);
  prep2<<<dim3(16), dim3(256), 0, stream>>>(part, wqkv0, qkvg);

  fused_kernel<<<dim3(NP / PTILE, NB), dim3(512), LDS_SZ, stream>>>(
      x, y, qkvg, (float*)d_out,
      wq0_hi, wc_hi, wc_lo, wo1_hi, wo1_lo, bq, bout1);
}

// Round 17
// 229.787 us; speedup vs baseline: 1.2201x; 1.2201x over previous
//
#include <hip/hip_runtime.h>

typedef unsigned short u16;
typedef unsigned int   u32;
typedef short bf16x8 __attribute__((ext_vector_type(8)));
typedef float f32x16 __attribute__((ext_vector_type(16)));

#define NB    8
#define NP    3136
#define DIM   256
#define PTILE 16
#define NEGM  (-100.0f)
#define QKSCALE 0.17677669529663687f

// LDS 52K, time-multiplexed (every write lands in a provably-dead hole):
//  staging: A0h @0-16K
//  s0 GEMM1: reads A0; scatter Q0 @16-32K, K0 @32-48K
//  dots0: reads Q0/K0; p0 @0-8K (A0 dead)
//  PV0: reads p0; writes A1h @16-48K (Q0/K0 dead)
//  s1 Qpass: reads A1h; scatter Q1 @0-16K (p0 dead)
//  s1 K/V passes -> regs (packed bf16); barrier; K1 scatter @16-48K (A1h dead)
//  dots1: reads Q1 @0-16K, K1 @16-48K; p1 @48-52K
//  PV1: reads p1; attnout1 hi @0-16K, lo @16-32K (Q1/K1 dead)
//  GEMM2: reads hi/lo.
#define LDS_SZ  53248
#define Q0B     16384
#define K0B     32768
#define A1B     16384
#define K1B     16384
#define P1B     49152
#define AO1LB   16384

__device__ __forceinline__ float bflo(u32 w) { return __uint_as_float(w << 16); }
__device__ __forceinline__ float bfhi(u32 w) { return __uint_as_float(w & 0xffff0000u); }

__device__ __forceinline__ u32 cvt_pk(float a, float b) {
  u32 r;
  asm("v_cvt_pk_bf16_f32 %0, %1, %2" : "=v"(r) : "v"(a), "v"(b));
  return r;
}

__device__ __forceinline__ void phase_fence() { __builtin_amdgcn_sched_barrier(0); }

template<int MASKI>
__device__ __forceinline__ float maskv(int i, int j) {
  if (MASKI == 0) return ((i ^ j) == 3) ? NEGM : 0.f;
  return (i >= 2 || ((i ^ j) & 1)) ? NEGM : 0.f;
}

#define FRAG(nt, ks) ((((size_t)(nt) * 16 + (ks)) * 64 + lane) * 8)

// ---------------- prologue kernels (R15-proven structure) ----------------
__device__ __forceinline__ void pack4(const float* __restrict__ W,
                                      u16* __restrict__ hi, u16* __restrict__ lo,
                                      int is_qkv, int pair0, int tid) {
  const int p    = pair0 + (tid >> 6);
  const int lane = tid & 63;
  const int nt = p >> 4, ks = p & 15;
  const int n  = nt * 32 + (lane & 31);
  const int k0 = ks * 16 + ((lane >> 5) << 3);
  const float scale = (is_qkv && n < 256) ? QKSCALE : 1.0f;
  const float* src = W + (size_t)n * 256 + k0;
  const size_t o = (((size_t)nt * 16 + ks) * 64 + lane) * 8;
#pragma unroll
  for (int j = 0; j < 8; j++) {
    float v = src[j] * scale;
    u32 wh = cvt_pk(v, v);
    hi[o + j] = (u16)wh;
    if (lo) lo[o + j] = (u16)cvt_pk(v - bflo(wh), 0.f);
  }
}

// blocks: [0,1568) mean partials; [1568,1664) pack wqkv0; [1664,1696) pack
// wout1; [1696,2464) Wc rows (parallel, global f32); [2464,2467) combo_b.
__global__ __launch_bounds__(256)
void prep1(const float* __restrict__ x, const float* __restrict__ y,
           float* __restrict__ part,
           const float* __restrict__ wqkv0, u16* __restrict__ wq0_hi,
           const float* __restrict__ wout1, u16* __restrict__ wo1_hi, u16* __restrict__ wo1_lo,
           const float* __restrict__ wqkv1, const float* __restrict__ wout0,
           float* __restrict__ Wc,
           const float* __restrict__ bout0, float* __restrict__ bq) {
  __shared__ float srow[256];
  const int bid = blockIdx.x;
  const int tid = threadIdx.x;
  if (bid < 1568) {                      // mean partials (98 chunks x 16 ab)
    const int ab = bid / 98;
    const int chunk = bid - ab * 98;
    const int b = ab & 7;
    const float* src = (ab >> 3) ? y : x;
    float s = 0.f;
    const int p0 = chunk * 32;           // 3136 = 98*32
#pragma unroll 4
    for (int i = 0; i < 32; i++)
      s += src[((size_t)b * NP + p0 + i) * DIM + tid];
    part[((size_t)ab * 98 + chunk) * DIM + tid] = s;
  } else if (bid < 1664) {               // pack wqkv0 hi-only (384 pairs)
    pack4(wqkv0, wq0_hi, nullptr, 1, (bid - 1568) * 4, tid);
  } else if (bid < 1696) {               // pack wout1 hi+lo (128 pairs)
    pack4(wout1, wo1_hi, wo1_lo, 0, (bid - 1664) * 4, tid);
  } else if (bid < 2464) {               // Wc row n = Wqkv1 . Wout0
    const int n = bid - 1696;
    srow[tid] = wqkv1[(size_t)n * 256 + tid];
    __syncthreads();
    float acc = 0.f;
#pragma unroll 8
    for (int d = 0; d < 256; d++)
      acc += srow[d] * wout0[(size_t)d * 256 + tid];
    Wc[(size_t)n * 256 + tid] = acc;
  } else {                               // bq = Wqkv1 . bout0 (Q rows scaled)
    const int n = (bid - 2464) * 256 + tid;
    float s = 0.f;
    for (int d = 0; d < 256; d += 4) {
      const float4 w = *(const float4*)(wqkv1 + (size_t)n * 256 + d);
      const float4 bv = *(const float4*)(bout0 + d);
      s += w.x * bv.x + w.y * bv.y + w.z * bv.z + w.w * bv.w;
    }
    bq[n] = (n < 256) ? s * QKSCALE : s;
  }
}

// blocks [0,16): mean_final + qkvg (g stays in smem); [16,112): pack Wc.
__global__ __launch_bounds__(256)
void prep2(const float* __restrict__ part, const float* __restrict__ wqkv0,
           float* __restrict__ qkvg,
           const float* __restrict__ Wc, u16* __restrict__ wc_hi, u16* __restrict__ wc_lo) {
  __shared__ float srow[256];
  const int bid = blockIdx.x;
  const int tid = threadIdx.x;
  if (bid < 16) {
    float s = 0.f;
    for (int c = 0; c < 98; c++) s += part[((size_t)bid * 98 + c) * DIM + tid];
    srow[tid] = s * (1.0f / 3136.0f);
    __syncthreads();
    const int bt = (bid < 8) ? (2 * bid) : (2 * (bid - 8) + 1);
#pragma unroll
    for (int sct = 0; sct < 3; sct++) {
      const int e = sct * 256 + tid;
      float acc = 0.f;
      for (int d = 0; d < 256; d += 4) {
        const float4 w = *(const float4*)(wqkv0 + (size_t)e * 256 + d);
        acc += w.x * srow[d] + w.y * srow[d + 1] + w.z * srow[d + 2] + w.w * srow[d + 3];
      }
      qkvg[(size_t)bt * 768 + e] = (e < 256) ? acc * QKSCALE : acc;
    }
  } else {
    pack4(Wc, wc_hi, wc_lo, 1, (bid - 16) * 4, tid);
  }
}

// ---------------- fused double-stage kernel ----------------
__global__ __launch_bounds__(512, 6)
void fused_kernel(const float* __restrict__ x, const float* __restrict__ y,
                  const float* __restrict__ qkvg, float* __restrict__ outp,
                  const u16* __restrict__ wq0_hi,
                  const u16* __restrict__ wc_hi,  const u16* __restrict__ wc_lo,
                  const u16* __restrict__ wo1_hi, const u16* __restrict__ wo1_lo,
                  const float* __restrict__ bq,   const float* __restrict__ bout1) {
  extern __shared__ char lds[];
  const int tid  = threadIdx.x;
  const int lane = tid & 63;
  const int wave = tid >> 6;         // 0..7
  const int cl   = lane & 31;
  const int rh5  = lane >> 5;        // 0/1
  const int kgrp = rh5 << 3;
  const int b    = blockIdx.y;
  const int pos0 = blockIdx.x * PTILE;
  const int apos = wave * 2 + rh5;   // 0..15
  const int ah   = (lane >> 2) & 7;  // head
  const int adq  = lane & 3;         // 8 dims each
  const float* qg = qkvg + (size_t)(b * 2) * 768;

  // ---- stage A0 (32 rows = 16pos x {x,y}) bf16-hi only @0..16K ----
  {
    const int r   = tid >> 4;          // 0..31
    const int cb  = (tid & 15) * 16;
    const int pos = pos0 + (r >> 1);
    const float* src = ((r & 1) ? y : x) + ((size_t)b * NP + pos) * DIM;
#pragma unroll
    for (int u = 0; u < 4; u++) {
      const int col = cb + u * 4;
      float4 v = *(const float4*)(src + col);
      uint2 hw;
      hw.x = cvt_pk(v.x, v.y);
      hw.y = cvt_pk(v.z, v.w);
      *(uint2*)(lds + ((r * 512 + col * 2) ^ ((r & 15) << 4))) = hw;
    }
  }
  __syncthreads();
  phase_fence();

  // ================= STAGE 0 =================
  f32x16 av;
  {
    f32x16 aq, ak;
#pragma unroll
    for (int i = 0; i < 16; i++) { aq[i] = 0.f; ak[i] = 0.f; av[i] = 0.f; }
#pragma unroll 2
    for (int ks = 0; ks < 16; ks++) {
      const int k0 = ks * 16 + kgrp;
      bf16x8 ahf = *(const bf16x8*)(lds + ((cl * 512 + k0 * 2) ^ ((cl & 15) << 4)));
      bf16x8 bQ = *(const bf16x8*)(wq0_hi + FRAG(wave, ks));
      bf16x8 bK = *(const bf16x8*)(wq0_hi + FRAG(8 + wave, ks));
      bf16x8 bV = *(const bf16x8*)(wq0_hi + FRAG(16 + wave, ks));
      __builtin_amdgcn_s_setprio(1);
      aq = __builtin_amdgcn_mfma_f32_32x32x16_bf16(ahf, bQ, aq, 0, 0, 0);
      ak = __builtin_amdgcn_mfma_f32_32x32x16_bf16(ahf, bK, ak, 0, 0, 0);
      av = __builtin_amdgcn_mfma_f32_32x32x16_bf16(ahf, bV, av, 0, 0, 0);
      __builtin_amdgcn_s_setprio(0);
    }
    const int sw0 = ((cl ^ wave) & 7) << 3;
    const int bQd = Q0B + wave * 2048 + cl * 64;
    const int bKd = K0B + wave * 2048 + cl * 64;
#pragma unroll
    for (int gq = 0; gq < 4; gq++) {
      const int p20 = 8 * gq + 4 * rh5;
      uint2 wv;
      wv.x = cvt_pk(aq[4 * gq + 0], aq[4 * gq + 1]);
      wv.y = cvt_pk(aq[4 * gq + 2], aq[4 * gq + 3]);
      *(uint2*)(lds + bQd + ((p20 * 2) ^ sw0)) = wv;
      wv.x = cvt_pk(ak[4 * gq + 0], ak[4 * gq + 1]);
      wv.y = cvt_pk(ak[4 * gq + 2], ak[4 * gq + 3]);
      *(uint2*)(lds + bKd + ((p20 * 2) ^ sw0)) = wv;
    }
  }
  __syncthreads();   // Q0/K0 visible; A0 dead
  phase_fence();

  // ---- dots0: p0 -> @0-8K (A0 dead) ----
  {
    const int e0 = ah * 32 + adq * 8;
    float dots[4][4];
#pragma unroll
    for (int i = 0; i < 4; i++)
#pragma unroll
      for (int j = 0; j < 4; j++) dots[i][j] = 0.f;
#pragma unroll 2
    for (int dd = 0; dd < 8; dd++) {
      const int d = adq * 8 + dd;
      const int sw = ((d ^ ah) & 7) << 3;
      u32 qw = *(const u32*)(lds + Q0B + ah * 2048 + d * 64 + ((apos * 4) ^ sw));
      u32 kw = *(const u32*)(lds + K0B + ah * 2048 + d * 64 + ((apos * 4) ^ sw));
      float q[4] = { bflo(qw), bfhi(qw), qg[e0 + dd], qg[768 + e0 + dd] };
      float k[4] = { bflo(kw), bfhi(kw), qg[256 + e0 + dd], qg[1024 + e0 + dd] };
#pragma unroll
      for (int i = 0; i < 4; i++)
#pragma unroll
        for (int j = 0; j < 4; j++) dots[i][j] += q[i] * k[j];
    }
#pragma unroll
    for (int i = 0; i < 4; i++)
#pragma unroll
      for (int j = 0; j < 4; j++) {
        float s = dots[i][j];
        s += __shfl_xor(s, 1);
        s += __shfl_xor(s, 2);
        dots[i][j] = s + maskv<0>(i, j);
      }
    if (adq == 0) {
#pragma unroll
      for (int i = 0; i < 4; i++) {
        const float mx = fmaxf(fmaxf(dots[i][0], dots[i][1]), fmaxf(dots[i][2], dots[i][3]));
        const float e0_ = __expf(dots[i][0] - mx), e1_ = __expf(dots[i][1] - mx);
        const float e2_ = __expf(dots[i][2] - mx), e3_ = __expf(dots[i][3] - mx);
        const float inv = 1.f / (e0_ + e1_ + e2_ + e3_);
        float4 pv_ = { e0_ * inv, e1_ * inv, e2_ * inv, e3_ * inv };
        *(float4*)(lds + ((apos * 8 + ah) * 4 + i) * 16) = pv_;
      }
    }
  }
  __syncthreads();   // p0 visible; Q0/K0 reads done
  phase_fence();

  // ---- PV0 + attnout0 write: A1h bf16 @16-48K (Q0/K0 dead); p0 @0-8K ----
  {
    const float vg2 = qg[512 + wave * 32 + cl];
    const float vg3 = qg[768 + 512 + wave * 32 + cl];
    const int c = wave * 32 + cl;
#pragma unroll
    for (int gq = 0; gq < 4; gq++) {
#pragma unroll
      for (int pp = 0; pp < 2; pp++) {
        const int pos = 4 * gq + 2 * rh5 + pp;
        const float v0 = av[4 * gq + 2 * pp], v1 = av[4 * gq + 2 * pp + 1];
#pragma unroll
        for (int i = 0; i < 4; i++) {
          float4 pi = *(const float4*)(lds + ((pos * 8 + wave) * 4 + i) * 16);
          const float o = pi.x * v0 + pi.y * v1 + pi.z * vg2 + pi.w * vg3;
          const int R = pos * 4 + i;
          *(u16*)(lds + A1B + ((R * 512 + c * 2) ^ ((R & 15) << 4))) = (u16)cvt_pk(o, o);
        }
      }
    }
  }
  __syncthreads();   // A1 visible; p0 reads done
  phase_fence();

  // ================= STAGE 1 (A = A1h @16-48K) =================
  // Q pass (2-pass), scatter Q1 @0-16K (p0 dead)
  {
    f32x16 aq0, aq1;
#pragma unroll
    for (int i = 0; i < 16; i++) { aq0[i] = 0.f; aq1[i] = 0.f; }
#pragma unroll 1
    for (int ks = 0; ks < 16; ks++) {
      const int k0 = ks * 16 + kgrp;
      bf16x8 ah0 = *(const bf16x8*)(lds + A1B + ((cl * 512 + k0 * 2) ^ ((cl & 15) << 4)));
      bf16x8 ah1 = *(const bf16x8*)(lds + A1B + (((32 + cl) * 512 + k0 * 2) ^ (((32 + cl) & 15) << 4)));
      bf16x8 bh = *(const bf16x8*)(wc_hi + FRAG(wave, ks));
      bf16x8 bl = *(const bf16x8*)(wc_lo + FRAG(wave, ks));
      __builtin_amdgcn_s_setprio(1);
      aq0 = __builtin_amdgcn_mfma_f32_32x32x16_bf16(ah0, bh, aq0, 0, 0, 0);
      aq0 = __builtin_amdgcn_mfma_f32_32x32x16_bf16(ah0, bl, aq0, 0, 0, 0);
      aq1 = __builtin_amdgcn_mfma_f32_32x32x16_bf16(ah1, bh, aq1, 0, 0, 0);
      aq1 = __builtin_amdgcn_mfma_f32_32x32x16_bf16(ah1, bl, aq1, 0, 0, 0);
      __builtin_amdgcn_s_setprio(0);
    }
    const float qb = bq[wave * 32 + cl];
    const int swq = ((cl ^ wave) & 7) << 3;
    const int bQ1 = wave * 2048 + cl * 64;   // @0-16K
#pragma unroll
    for (int gq = 0; gq < 4; gq++) {
      const int posA = 2 * gq + rh5;
      *(u32*)(lds + bQ1 + ((posA * 4) ^ swq)) =
          cvt_pk(aq0[4 * gq] + qb, aq0[4 * gq + 1] + qb);
      *(u32*)(lds + bQ1 + (((posA + 8) * 4) ^ swq)) =
          cvt_pk(aq1[4 * gq] + qb, aq1[4 * gq + 1] + qb);
    }
  }
  phase_fence();
  // K pass: accumulate, PACK to bf16 (16 u32 held)
  uint2 kp0[4], kp1[4];
  {
    f32x16 ak0, ak1;
#pragma unroll
    for (int i = 0; i < 16; i++) { ak0[i] = 0.f; ak1[i] = 0.f; }
#pragma unroll 1
    for (int ks = 0; ks < 16; ks++) {
      const int k0 = ks * 16 + kgrp;
      bf16x8 ah0 = *(const bf16x8*)(lds + A1B + ((cl * 512 + k0 * 2) ^ ((cl & 15) << 4)));
      bf16x8 ah1 = *(const bf16x8*)(lds + A1B + (((32 + cl) * 512 + k0 * 2) ^ (((32 + cl) & 15) << 4)));
      bf16x8 bh = *(const bf16x8*)(wc_hi + FRAG(8 + wave, ks));
      bf16x8 bl = *(const bf16x8*)(wc_lo + FRAG(8 + wave, ks));
      __builtin_amdgcn_s_setprio(1);
      ak0 = __builtin_amdgcn_mfma_f32_32x32x16_bf16(ah0, bh, ak0, 0, 0, 0);
      ak0 = __builtin_amdgcn_mfma_f32_32x32x16_bf16(ah0, bl, ak0, 0, 0, 0);
      ak1 = __builtin_amdgcn_mfma_f32_32x32x16_bf16(ah1, bh, ak1, 0, 0, 0);
      ak1 = __builtin_amdgcn_mfma_f32_32x32x16_bf16(ah1, bl, ak1, 0, 0, 0);
      __builtin_amdgcn_s_setprio(0);
    }
    const float kb = bq[256 + wave * 32 + cl];
#pragma unroll
    for (int gq = 0; gq < 4; gq++) {
      kp0[gq].x = cvt_pk(ak0[4 * gq + 0] + kb, ak0[4 * gq + 1] + kb);
      kp0[gq].y = cvt_pk(ak0[4 * gq + 2] + kb, ak0[4 * gq + 3] + kb);
      kp1[gq].x = cvt_pk(ak1[4 * gq + 0] + kb, ak1[4 * gq + 1] + kb);
      kp1[gq].y = cvt_pk(ak1[4 * gq + 2] + kb, ak1[4 * gq + 3] + kb);
    }
  }
  phase_fence();
  // V pass: 2-pass bf16; accs PACKED to bf16 at end (16 u32 held, not 32 f32)
  uint2 avp0[4], avp1[4];
  {
    f32x16 av0, av1;
#pragma unroll
    for (int i = 0; i < 16; i++) { av0[i] = 0.f; av1[i] = 0.f; }
#pragma unroll 1
    for (int ks = 0; ks < 16; ks++) {
      const int k0 = ks * 16 + kgrp;
      bf16x8 ah0 = *(const bf16x8*)(lds + A1B + ((cl * 512 + k0 * 2) ^ ((cl & 15) << 4)));
      bf16x8 ah1 = *(const bf16x8*)(lds + A1B + (((32 + cl) * 512 + k0 * 2) ^ (((32 + cl) & 15) << 4)));
      bf16x8 bh = *(const bf16x8*)(wc_hi + FRAG(16 + wave, ks));
      bf16x8 bl = *(const bf16x8*)(wc_lo + FRAG(16 + wave, ks));
      __builtin_amdgcn_s_setprio(1);
      av0 = __builtin_amdgcn_mfma_f32_32x32x16_bf16(ah0, bh, av0, 0, 0, 0);
      av0 = __builtin_amdgcn_mfma_f32_32x32x16_bf16(ah0, bl, av0, 0, 0, 0);
      av1 = __builtin_amdgcn_mfma_f32_32x32x16_bf16(ah1, bh, av1, 0, 0, 0);
      av1 = __builtin_amdgcn_mfma_f32_32x32x16_bf16(ah1, bl, av1, 0, 0, 0);
      __builtin_amdgcn_s_setprio(0);
    }
    const float vb = bq[512 + wave * 32 + cl];
#pragma unroll
    for (int gq = 0; gq < 4; gq++) {
      avp0[gq].x = cvt_pk(av0[4 * gq + 0] + vb, av0[4 * gq + 1] + vb);
      avp0[gq].y = cvt_pk(av0[4 * gq + 2] + vb, av0[4 * gq + 3] + vb);
      avp1[gq].x = cvt_pk(av1[4 * gq + 0] + vb, av1[4 * gq + 1] + vb);
      avp1[gq].y = cvt_pk(av1[4 * gq + 2] + vb, av1[4 * gq + 3] + vb);
    }
  }
  __syncthreads();   // A1 dead; Q1 visible
  phase_fence();

  // ---- scatter K1 [h][d][p4=64] @16-48K from packed regs ----
  {
    const int swk = ((cl ^ wave) & 7) << 4;
    const int bK1 = K1B + wave * 4096 + cl * 128;
#pragma unroll
    for (int gq = 0; gq < 4; gq++) {
      const int R0a = 8 * gq + 4 * rh5;
      *(uint2*)(lds + bK1 + ((R0a * 2) ^ swk)) = kp0[gq];
      *(uint2*)(lds + bK1 + (((R0a + 32) * 2) ^ swk)) = kp1[gq];
    }
  }
  __syncthreads();   // K1 visible
  phase_fence();

  // ---- dots1: Q1 @0-16K, K1 @16-48K; p1 @48-52K ----
  {
    float dots[2][4];
#pragma unroll
    for (int i = 0; i < 2; i++)
#pragma unroll
      for (int j = 0; j < 4; j++) dots[i][j] = 0.f;
#pragma unroll 2
    for (int dd = 0; dd < 8; dd++) {
      const int d = adq * 8 + dd;
      u32 qw = *(const u32*)(lds + ah * 2048 + d * 64 +
                             ((apos * 4) ^ (((d ^ ah) & 7) << 3)));
      uint2 kw = *(const uint2*)(lds + K1B + ah * 4096 + d * 128 +
                                 ((apos * 8) ^ (((d ^ ah) & 7) << 4)));
      float q[2] = { bflo(qw), bfhi(qw) };
      float k[4] = { bflo(kw.x), bfhi(kw.x), bflo(kw.y), bfhi(kw.y) };
#pragma unroll
      for (int i = 0; i < 2; i++)
#pragma unroll
        for (int j = 0; j < 4; j++) dots[i][j] += q[i] * k[j];
    }
#pragma unroll
    for (int i = 0; i < 2; i++)
#pragma unroll
      for (int j = 0; j < 4; j++) {
        float s = dots[i][j];
        s += __shfl_xor(s, 1);
        s += __shfl_xor(s, 2);
        dots[i][j] = s + maskv<1>(i, j);
      }
    if (adq == 0) {
#pragma unroll
      for (int i = 0; i < 2; i++) {
        const float mx = fmaxf(fmaxf(dots[i][0], dots[i][1]), fmaxf(dots[i][2], dots[i][3]));
        const float e0_ = __expf(dots[i][0] - mx), e1_ = __expf(dots[i][1] - mx);
        const float e2_ = __expf(dots[i][2] - mx), e3_ = __expf(dots[i][3] - mx);
        const float inv = 1.f / (e0_ + e1_ + e2_ + e3_);
        float4 pv_ = { e0_ * inv, e1_ * inv, e2_ * inv, e3_ * inv };
        *(float4*)(lds + P1B + ((apos * 8 + ah) * 2 + i) * 16) = pv_;
      }
    }
  }
  __syncthreads();   // p1 visible; Q1/K1 reads done
  phase_fence();

  // ---- PV1 + attnout1 write (hi @0-16K, lo @16-32K; p1 @48-52K) ----
  {
    const int c = wave * 32 + cl;
#pragma unroll
    for (int gq = 0; gq < 4; gq++) {
      const int posA = 2 * gq + rh5;
      const float a00 = bflo(avp0[gq].x), a01 = bfhi(avp0[gq].x);
      const float a02 = bflo(avp0[gq].y), a03 = bfhi(avp0[gq].y);
      const float a10 = bflo(avp1[gq].x), a11 = bfhi(avp1[gq].x);
      const float a12 = bflo(avp1[gq].y), a13 = bfhi(avp1[gq].y);
#pragma unroll
      for (int i = 0; i < 2; i++) {
        float4 pa = *(const float4*)(lds + P1B + ((posA * 8 + wave) * 2 + i) * 16);
        const float o0 = pa.x * a00 + pa.y * a01 + pa.z * a02 + pa.w * a03;
        const int r0 = posA * 2 + i;
        const u32 h0 = cvt_pk(o0, o0);
        const int bo0 = (r0 * 512 + c * 2) ^ ((r0 & 15) << 4);
        *(u16*)(lds + bo0) = (u16)h0;
        *(u16*)(lds + AO1LB + bo0) = (u16)cvt_pk(o0 - bflo(h0), 0.f);
        float4 pb = *(const float4*)(lds + P1B + (((posA + 8) * 8 + wave) * 2 + i) * 16);
        const float o1 = pb.x * a10 + pb.y * a11 + pb.z * a12 + pb.w * a13;
        const int r1 = (posA + 8) * 2 + i;
        const u32 h1 = cvt_pk(o1, o1);
        const int bo1 = (r1 * 512 + c * 2) ^ ((r1 & 15) << 4);
        *(u16*)(lds + bo1) = (u16)h1;
        *(u16*)(lds + AO1LB + bo1) = (u16)cvt_pk(o1 - bflo(h1), 0.f);
      }
    }
  }
  __syncthreads();   // attnout1 visible; p1 reads done
  phase_fence();

  // ---- GEMM2 (3-pass) + epilogue ----
  {
    f32x16 acc2;
#pragma unroll
    for (int i = 0; i < 16; i++) acc2[i] = 0.f;
#pragma unroll 2
    for (int ks = 0; ks < 16; ks++) {
      const int k0 = ks * 16 + kgrp;
      const int bo = (cl * 512 + k0 * 2) ^ ((cl & 15) << 4);
      bf16x8 ahf = *(const bf16x8*)(lds + bo);
      bf16x8 alf = *(const bf16x8*)(lds + AO1LB + bo);
      bf16x8 bh = *(const bf16x8*)(wo1_hi + FRAG(wave, ks));
      bf16x8 bl = *(const bf16x8*)(wo1_lo + FRAG(wave, ks));
      __builtin_amdgcn_s_setprio(1);
      acc2 = __builtin_amdgcn_mfma_f32_32x32x16_bf16(ahf, bh, acc2, 0, 0, 0);
      acc2 = __builtin_amdgcn_mfma_f32_32x32x16_bf16(ahf, bl, acc2, 0, 0, 0);
      acc2 = __builtin_amdgcn_mfma_f32_32x32x16_bf16(alf, bh, acc2, 0, 0, 0);
      __builtin_amdgcn_s_setprio(0);
    }
    const int c = wave * 32 + cl;
    const float bc = bout1[c];
    const size_t TOT = (size_t)NB * NP * DIM;
#pragma unroll
    for (int i = 0; i < 16; i++) {
      const int r = (i & 3) + ((i >> 2) << 3) + 4 * rh5;
      const int pos = pos0 + (r >> 1);
      const float v = acc2[i] + bc;
      if ((r & 1) == 0) outp[((size_t)b * NP + pos) * DIM + c] = v;
      else              outp[TOT + ((size_t)b * NP + pos) * DIM + c] = v;
    }
  }
}

extern "C" void kernel_launch(void* const* d_in, const int* in_sizes, int n_in,
                              void* d_out, int out_size, void* d_ws, size_t ws_size,
                              hipStream_t stream) {
  const float* x     = (const float*)d_in[0];
  const float* y     = (const float*)d_in[1];
  const float* wqkv0 = (const float*)d_in[2];
  const float* wout0 = (const float*)d_in[3];
  const float* bout0 = (const float*)d_in[4];
  const float* wqkv1 = (const float*)d_in[5];
  const float* wout1 = (const float*)d_in[6];
  const float* bout1 = (const float*)d_in[7];

  float* part = (float*)d_ws;                        // 16*98*256
  float* Wc   = part + (size_t)16 * 98 * DIM;        // 768*256
  float* bq   = Wc + (size_t)768 * 256;              // 768
  float* qkvg = bq + 768;                            // 8*2*768
  u16* w = (u16*)(qkvg + (size_t)8 * 2 * 768);
  u16* wq0_hi = w; w += (size_t)768 * 256;
  u16* wc_hi  = w; w += (size_t)768 * 256;
  u16* wc_lo  = w; w += (size_t)768 * 256;
  u16* wo1_hi = w; w += (size_t)256 * 256;
  u16* wo1_lo = w; w += (size_t)256 * 256;

  prep1<<<dim3(2467), dim3(256), 0, stream>>>(
      x, y, part, wqkv0, wq0_hi, wout1, wo1_hi, wo1_lo,
      wqkv1, wout0, Wc, bout0, bq);
  prep2<<<dim3(112), dim3(256), 0, stream>>>(part, wqkv0, qkvg, Wc, wc_hi, wc_lo);

  fused_kernel<<<dim3(NP / PTILE, NB), dim3(512), LDS_SZ, stream>>>(
      x, y, qkvg, (float*)d_out,
      wq0_hi, wc_hi, wc_lo, wo1_hi, wo1_lo, bq, bout1);
}

// Round 18
// 219.929 us; speedup vs baseline: 1.2748x; 1.0448x over previous
//
#include <hip/hip_runtime.h>

typedef unsigned short u16;
typedef unsigned int   u32;
typedef short bf16x8 __attribute__((ext_vector_type(8)));
typedef float f32x16 __attribute__((ext_vector_type(16)));

#define NB    8
#define NP    3136
#define DIM   256
#define PTILE 16
#define NEGM  (-100.0f)
#define QKSCALE 0.17677669529663687f

// LDS 64K, time-multiplexed (R15-proven map):
// stage0: A0h@0-16K | Q0@16-32K | K0@32-48K | p0@48-56K
//   -> attnout0: A1h (bf16) @0-32K            (Q1 slot @48-64K)
// stage1: A1h@0-32K; Q1@48-64K; then K1@0-32K, p1@32-36K;
//   attnout1 hi@0-16K lo@16-32K -> GEMM2.
#define LDS_SZ  65536
#define Q0B     16384
#define K0B     32768
#define P0B     49152
#define Q1B     49152
#define P1B     32768
#define AO1LB   16384

__device__ __forceinline__ float bflo(u32 w) { return __uint_as_float(w << 16); }
__device__ __forceinline__ float bfhi(u32 w) { return __uint_as_float(w & 0xffff0000u); }

__device__ __forceinline__ u32 cvt_pk(float a, float b) {
  u32 r;
  asm("v_cvt_pk_bf16_f32 %0, %1, %2" : "=v"(r) : "v"(a), "v"(b));
  return r;
}

__device__ __forceinline__ void phase_fence() { __builtin_amdgcn_sched_barrier(0); }

template<int MASKI>
__device__ __forceinline__ float maskv(int i, int j) {
  if (MASKI == 0) return ((i ^ j) == 3) ? NEGM : 0.f;
  return (i >= 2 || ((i ^ j) & 1)) ? NEGM : 0.f;
}

#define FRAG(nt, ks) ((((size_t)(nt) * 16 + (ks)) * 64 + lane) * 8)

// ---------------- prologue kernels (R15-proven structure) ----------------
__device__ __forceinline__ void pack4(const float* __restrict__ W,
                                      u16* __restrict__ hi, u16* __restrict__ lo,
                                      int is_qkv, int pair0, int tid) {
  const int p    = pair0 + (tid >> 6);
  const int lane = tid & 63;
  const int nt = p >> 4, ks = p & 15;
  const int n  = nt * 32 + (lane & 31);
  const int k0 = ks * 16 + ((lane >> 5) << 3);
  const float scale = (is_qkv && n < 256) ? QKSCALE : 1.0f;
  const float* src = W + (size_t)n * 256 + k0;
  const size_t o = (((size_t)nt * 16 + ks) * 64 + lane) * 8;
#pragma unroll
  for (int j = 0; j < 8; j++) {
    float v = src[j] * scale;
    u32 wh = cvt_pk(v, v);
    hi[o + j] = (u16)wh;
    if (lo) lo[o + j] = (u16)cvt_pk(v - bflo(wh), 0.f);
  }
}

// blocks: [0,1568) mean partials; [1568,1664) pack wqkv0; [1664,1696) pack
// wout1; [1696,2464) Wc rows (parallel, global f32); [2464,2467) combo_b.
__global__ __launch_bounds__(256)
void prep1(const float* __restrict__ x, const float* __restrict__ y,
           float* __restrict__ part,
           const float* __restrict__ wqkv0, u16* __restrict__ wq0_hi,
           const float* __restrict__ wout1, u16* __restrict__ wo1_hi, u16* __restrict__ wo1_lo,
           const float* __restrict__ wqkv1, const float* __restrict__ wout0,
           float* __restrict__ Wc,
           const float* __restrict__ bout0, float* __restrict__ bq) {
  __shared__ float srow[256];
  const int bid = blockIdx.x;
  const int tid = threadIdx.x;
  if (bid < 1568) {                      // mean partials (98 chunks x 16 ab)
    const int ab = bid / 98;
    const int chunk = bid - ab * 98;
    const int b = ab & 7;
    const float* src = (ab >> 3) ? y : x;
    float s = 0.f;
    const int p0 = chunk * 32;           // 3136 = 98*32
#pragma unroll 4
    for (int i = 0; i < 32; i++)
      s += src[((size_t)b * NP + p0 + i) * DIM + tid];
    part[((size_t)ab * 98 + chunk) * DIM + tid] = s;
  } else if (bid < 1664) {               // pack wqkv0 hi-only (384 pairs)
    pack4(wqkv0, wq0_hi, nullptr, 1, (bid - 1568) * 4, tid);
  } else if (bid < 1696) {               // pack wout1 hi+lo (128 pairs)
    pack4(wout1, wo1_hi, wo1_lo, 0, (bid - 1664) * 4, tid);
  } else if (bid < 2464) {               // Wc row n = Wqkv1 . Wout0
    const int n = bid - 1696;
    srow[tid] = wqkv1[(size_t)n * 256 + tid];
    __syncthreads();
    float acc = 0.f;
#pragma unroll 8
    for (int d = 0; d < 256; d++)
      acc += srow[d] * wout0[(size_t)d * 256 + tid];
    Wc[(size_t)n * 256 + tid] = acc;
  } else {                               // bq = Wqkv1 . bout0 (Q rows scaled)
    const int n = (bid - 2464) * 256 + tid;
    float s = 0.f;
    for (int d = 0; d < 256; d += 4) {
      const float4 w = *(const float4*)(wqkv1 + (size_t)n * 256 + d);
      const float4 bv = *(const float4*)(bout0 + d);
      s += w.x * bv.x + w.y * bv.y + w.z * bv.z + w.w * bv.w;
    }
    bq[n] = (n < 256) ? s * QKSCALE : s;
  }
}

// blocks [0,16): mean_final + qkvg (g stays in smem); [16,112): pack Wc.
__global__ __launch_bounds__(256)
void prep2(const float* __restrict__ part, const float* __restrict__ wqkv0,
           float* __restrict__ qkvg,
           const float* __restrict__ Wc, u16* __restrict__ wc_hi, u16* __restrict__ wc_lo) {
  __shared__ float srow[256];
  const int bid = blockIdx.x;
  const int tid = threadIdx.x;
  if (bid < 16) {
    float s = 0.f;
    for (int c = 0; c < 98; c++) s += part[((size_t)bid * 98 + c) * DIM + tid];
    srow[tid] = s * (1.0f / 3136.0f);
    __syncthreads();
    const int bt = (bid < 8) ? (2 * bid) : (2 * (bid - 8) + 1);
#pragma unroll
    for (int sct = 0; sct < 3; sct++) {
      const int e = sct * 256 + tid;
      float acc = 0.f;
      for (int d = 0; d < 256; d += 4) {
        const float4 w = *(const float4*)(wqkv0 + (size_t)e * 256 + d);
        acc += w.x * srow[d] + w.y * srow[d + 1] + w.z * srow[d + 2] + w.w * srow[d + 3];
      }
      qkvg[(size_t)bt * 768 + e] = (e < 256) ? acc * QKSCALE : acc;
    }
  } else {
    pack4(Wc, wc_hi, wc_lo, 1, (bid - 16) * 4, tid);
  }
}

// ---------------- fused double-stage kernel (R15 config: 512,4 / 64K) -----
__global__ __launch_bounds__(512, 4)
void fused_kernel(const float* __restrict__ x, const float* __restrict__ y,
                  const float* __restrict__ qkvg, float* __restrict__ outp,
                  const u16* __restrict__ wq0_hi,
                  const u16* __restrict__ wc_hi,  const u16* __restrict__ wc_lo,
                  const u16* __restrict__ wo1_hi, const u16* __restrict__ wo1_lo,
                  const float* __restrict__ bq,   const float* __restrict__ bout1) {
  extern __shared__ char lds[];
  const int tid  = threadIdx.x;
  const int lane = tid & 63;
  const int wave = tid >> 6;         // 0..7
  const int cl   = lane & 31;
  const int rh5  = lane >> 5;        // 0/1
  const int kgrp = rh5 << 3;
  const int b    = blockIdx.y;
  const int pos0 = blockIdx.x * PTILE;
  const int apos = wave * 2 + rh5;   // 0..15
  const int ah   = (lane >> 2) & 7;  // head
  const int adq  = lane & 3;         // 8 dims each
  const float* qg = qkvg + (size_t)(b * 2) * 768;

  // ---- stage A0 (32 rows = 16pos x {x,y}) bf16-hi only @0..16K ----
  {
    const int r   = tid >> 4;          // 0..31
    const int cb  = (tid & 15) * 16;
    const int pos = pos0 + (r >> 1);
    const float* src = ((r & 1) ? y : x) + ((size_t)b * NP + pos) * DIM;
#pragma unroll
    for (int u = 0; u < 4; u++) {
      const int col = cb + u * 4;
      float4 v = *(const float4*)(src + col);
      uint2 hw;
      hw.x = cvt_pk(v.x, v.y);
      hw.y = cvt_pk(v.z, v.w);
      *(uint2*)(lds + ((r * 512 + col * 2) ^ ((r & 15) << 4))) = hw;
    }
  }
  __syncthreads();
  phase_fence();

  // ================= STAGE 0 =================
  f32x16 av;
  {
    f32x16 aq, ak;
#pragma unroll
    for (int i = 0; i < 16; i++) { aq[i] = 0.f; ak[i] = 0.f; av[i] = 0.f; }
#pragma unroll 2
    for (int ks = 0; ks < 16; ks++) {
      const int k0 = ks * 16 + kgrp;
      bf16x8 ahf = *(const bf16x8*)(lds + ((cl * 512 + k0 * 2) ^ ((cl & 15) << 4)));
      bf16x8 bQ = *(const bf16x8*)(wq0_hi + FRAG(wave, ks));
      bf16x8 bK = *(const bf16x8*)(wq0_hi + FRAG(8 + wave, ks));
      bf16x8 bV = *(const bf16x8*)(wq0_hi + FRAG(16 + wave, ks));
      __builtin_amdgcn_s_setprio(1);
      aq = __builtin_amdgcn_mfma_f32_32x32x16_bf16(ahf, bQ, aq, 0, 0, 0);
      ak = __builtin_amdgcn_mfma_f32_32x32x16_bf16(ahf, bK, ak, 0, 0, 0);
      av = __builtin_amdgcn_mfma_f32_32x32x16_bf16(ahf, bV, av, 0, 0, 0);
      __builtin_amdgcn_s_setprio(0);
    }
    const int sw0 = ((cl ^ wave) & 7) << 3;
    const int bQd = Q0B + wave * 2048 + cl * 64;
    const int bKd = K0B + wave * 2048 + cl * 64;
#pragma unroll
    for (int gq = 0; gq < 4; gq++) {
      const int p20 = 8 * gq + 4 * rh5;
      uint2 wv;
      wv.x = cvt_pk(aq[4 * gq + 0], aq[4 * gq + 1]);
      wv.y = cvt_pk(aq[4 * gq + 2], aq[4 * gq + 3]);
      *(uint2*)(lds + bQd + ((p20 * 2) ^ sw0)) = wv;
      wv.x = cvt_pk(ak[4 * gq + 0], ak[4 * gq + 1]);
      wv.y = cvt_pk(ak[4 * gq + 2], ak[4 * gq + 3]);
      *(uint2*)(lds + bKd + ((p20 * 2) ^ sw0)) = wv;
    }
  }
  __syncthreads();   // Q0/K0 visible; A0 dead
  phase_fence();

  // ---- dots0: p0 -> @48-56K ----
  {
    const int e0 = ah * 32 + adq * 8;
    float dots[4][4];
#pragma unroll
    for (int i = 0; i < 4; i++)
#pragma unroll
      for (int j = 0; j < 4; j++) dots[i][j] = 0.f;
#pragma unroll 2
    for (int dd = 0; dd < 8; dd++) {
      const int d = adq * 8 + dd;
      const int sw = ((d ^ ah) & 7) << 3;
      u32 qw = *(const u32*)(lds + Q0B + ah * 2048 + d * 64 + ((apos * 4) ^ sw));
      u32 kw = *(const u32*)(lds + K0B + ah * 2048 + d * 64 + ((apos * 4) ^ sw));
      float q[4] = { bflo(qw), bfhi(qw), qg[e0 + dd], qg[768 + e0 + dd] };
      float k[4] = { bflo(kw), bfhi(kw), qg[256 + e0 + dd], qg[1024 + e0 + dd] };
#pragma unroll
      for (int i = 0; i < 4; i++)
#pragma unroll
        for (int j = 0; j < 4; j++) dots[i][j] += q[i] * k[j];
    }
#pragma unroll
    for (int i = 0; i < 4; i++)
#pragma unroll
      for (int j = 0; j < 4; j++) {
        float s = dots[i][j];
        s += __shfl_xor(s, 1);
        s += __shfl_xor(s, 2);
        dots[i][j] = s + maskv<0>(i, j);
      }
    if (adq == 0) {
#pragma unroll
      for (int i = 0; i < 4; i++) {
        const float mx = fmaxf(fmaxf(dots[i][0], dots[i][1]), fmaxf(dots[i][2], dots[i][3]));
        const float e0_ = __expf(dots[i][0] - mx), e1_ = __expf(dots[i][1] - mx);
        const float e2_ = __expf(dots[i][2] - mx), e3_ = __expf(dots[i][3] - mx);
        const float inv = 1.f / (e0_ + e1_ + e2_ + e3_);
        float4 pv_ = { e0_ * inv, e1_ * inv, e2_ * inv, e3_ * inv };
        *(float4*)(lds + P0B + ((apos * 8 + ah) * 4 + i) * 16) = pv_;
      }
    }
  }
  __syncthreads();   // p0 visible; Q0/K0 reads done -> 0-48K all dead
  phase_fence();

  // ---- PV0 + attnout0 write: A1h bf16 @0-32K; reads p0 @48-56K ----
  {
    const float vg2 = qg[512 + wave * 32 + cl];
    const float vg3 = qg[768 + 512 + wave * 32 + cl];
    const int c = wave * 32 + cl;
#pragma unroll
    for (int gq = 0; gq < 4; gq++) {
#pragma unroll
      for (int pp = 0; pp < 2; pp++) {
        const int pos = 4 * gq + 2 * rh5 + pp;
        const float v0 = av[4 * gq + 2 * pp], v1 = av[4 * gq + 2 * pp + 1];
#pragma unroll
        for (int i = 0; i < 4; i++) {
          float4 pi = *(const float4*)(lds + P0B + ((pos * 8 + wave) * 4 + i) * 16);
          const float o = pi.x * v0 + pi.y * v1 + pi.z * vg2 + pi.w * vg3;
          const int R = pos * 4 + i;
          *(u16*)(lds + ((R * 512 + c * 2) ^ ((R & 15) << 4))) = (u16)cvt_pk(o, o);
        }
      }
    }
  }
  __syncthreads();   // A1 visible; p0 reads done
  phase_fence();

  // ================= STAGE 1 =================
  // Q pass (2-pass), scatter Q1 immediately @48-64K (p0 dead)
  {
    f32x16 aq0, aq1;
#pragma unroll
    for (int i = 0; i < 16; i++) { aq0[i] = 0.f; aq1[i] = 0.f; }
#pragma unroll 2
    for (int ks = 0; ks < 16; ks++) {
      const int k0 = ks * 16 + kgrp;
      bf16x8 ah0 = *(const bf16x8*)(lds + ((cl * 512 + k0 * 2) ^ ((cl & 15) << 4)));
      bf16x8 ah1 = *(const bf16x8*)(lds + (((32 + cl) * 512 + k0 * 2) ^ (((32 + cl) & 15) << 4)));
      bf16x8 bh = *(const bf16x8*)(wc_hi + FRAG(wave, ks));
      bf16x8 bl = *(const bf16x8*)(wc_lo + FRAG(wave, ks));
      __builtin_amdgcn_s_setprio(1);
      aq0 = __builtin_amdgcn_mfma_f32_32x32x16_bf16(ah0, bh, aq0, 0, 0, 0);
      aq0 = __builtin_amdgcn_mfma_f32_32x32x16_bf16(ah0, bl, aq0, 0, 0, 0);
      aq1 = __builtin_amdgcn_mfma_f32_32x32x16_bf16(ah1, bh, aq1, 0, 0, 0);
      aq1 = __builtin_amdgcn_mfma_f32_32x32x16_bf16(ah1, bl, aq1, 0, 0, 0);
      __builtin_amdgcn_s_setprio(0);
    }
    const float qb = bq[wave * 32 + cl];
    const int swq = ((cl ^ wave) & 7) << 3;
    const int bQ1 = Q1B + wave * 2048 + cl * 64;
#pragma unroll
    for (int gq = 0; gq < 4; gq++) {
      const int posA = 2 * gq + rh5;
      *(u32*)(lds + bQ1 + ((posA * 4) ^ swq)) =
          cvt_pk(aq0[4 * gq] + qb, aq0[4 * gq + 1] + qb);
      *(u32*)(lds + bQ1 + (((posA + 8) * 4) ^ swq)) =
          cvt_pk(aq1[4 * gq] + qb, aq1[4 * gq + 1] + qb);
    }
  }
  phase_fence();
  // K pass: accumulate, then PACK to bf16 u32 regs (frees 32 f32 -> 16 u32)
  uint2 kp0[4], kp1[4];
  {
    f32x16 ak0, ak1;
#pragma unroll
    for (int i = 0; i < 16; i++) { ak0[i] = 0.f; ak1[i] = 0.f; }
#pragma unroll 2
    for (int ks = 0; ks < 16; ks++) {
      const int k0 = ks * 16 + kgrp;
      bf16x8 ah0 = *(const bf16x8*)(lds + ((cl * 512 + k0 * 2) ^ ((cl & 15) << 4)));
      bf16x8 ah1 = *(const bf16x8*)(lds + (((32 + cl) * 512 + k0 * 2) ^ (((32 + cl) & 15) << 4)));
      bf16x8 bh = *(const bf16x8*)(wc_hi + FRAG(8 + wave, ks));
      bf16x8 bl = *(const bf16x8*)(wc_lo + FRAG(8 + wave, ks));
      __builtin_amdgcn_s_setprio(1);
      ak0 = __builtin_amdgcn_mfma_f32_32x32x16_bf16(ah0, bh, ak0, 0, 0, 0);
      ak0 = __builtin_amdgcn_mfma_f32_32x32x16_bf16(ah0, bl, ak0, 0, 0, 0);
      ak1 = __builtin_amdgcn_mfma_f32_32x32x16_bf16(ah1, bh, ak1, 0, 0, 0);
      ak1 = __builtin_amdgcn_mfma_f32_32x32x16_bf16(ah1, bl, ak1, 0, 0, 0);
      __builtin_amdgcn_s_setprio(0);
    }
    const float kb = bq[256 + wave * 32 + cl];
#pragma unroll
    for (int gq = 0; gq < 4; gq++) {
      kp0[gq].x = cvt_pk(ak0[4 * gq + 0] + kb, ak0[4 * gq + 1] + kb);
      kp0[gq].y = cvt_pk(ak0[4 * gq + 2] + kb, ak0[4 * gq + 3] + kb);
      kp1[gq].x = cvt_pk(ak1[4 * gq + 0] + kb, ak1[4 * gq + 1] + kb);
      kp1[gq].y = cvt_pk(ak1[4 * gq + 2] + kb, ak1[4 * gq + 3] + kb);
    }
  }
  phase_fence();
  // V pass: 2-pass bf16
  f32x16 av0, av1;
  {
#pragma unroll
    for (int i = 0; i < 16; i++) { av0[i] = 0.f; av1[i] = 0.f; }
#pragma unroll 2
    for (int ks = 0; ks < 16; ks++) {
      const int k0 = ks * 16 + kgrp;
      bf16x8 ah0 = *(const bf16x8*)(lds + ((cl * 512 + k0 * 2) ^ ((cl & 15) << 4)));
      bf16x8 ah1 = *(const bf16x8*)(lds + (((32 + cl) * 512 + k0 * 2) ^ (((32 + cl) & 15) << 4)));
      bf16x8 bh = *(const bf16x8*)(wc_hi + FRAG(16 + wave, ks));
      bf16x8 bl = *(const bf16x8*)(wc_lo + FRAG(16 + wave, ks));
      __builtin_amdgcn_s_setprio(1);
      av0 = __builtin_amdgcn_mfma_f32_32x32x16_bf16(ah0, bh, av0, 0, 0, 0);
      av0 = __builtin_amdgcn_mfma_f32_32x32x16_bf16(ah0, bl, av0, 0, 0, 0);
      av1 = __builtin_amdgcn_mfma_f32_32x32x16_bf16(ah1, bh, av1, 0, 0, 0);
      av1 = __builtin_amdgcn_mfma_f32_32x32x16_bf16(ah1, bl, av1, 0, 0, 0);
      __builtin_amdgcn_s_setprio(0);
    }
    const float vb = bq[512 + wave * 32 + cl];
#pragma unroll
    for (int i = 0; i < 16; i++) { av0[i] += vb; av1[i] += vb; }
  }
  __syncthreads();   // A1 dead; Q1 visible
  phase_fence();

  // ---- scatter K1 [h][d][p4=64] @0-32K from packed regs ----
  {
    const int swk = ((cl ^ wave) & 7) << 4;
    const int bK1 = wave * 4096 + cl * 128;
#pragma unroll
    for (int gq = 0; gq < 4; gq++) {
      const int R0a = 8 * gq + 4 * rh5;
      *(uint2*)(lds + bK1 + ((R0a * 2) ^ swk)) = kp0[gq];
      *(uint2*)(lds + bK1 + (((R0a + 32) * 2) ^ swk)) = kp1[gq];
    }
  }
  __syncthreads();   // K1 visible
  phase_fence();

  // ---- dots1: rows 0,1 only ----
  {
    float dots[2][4];
#pragma unroll
    for (int i = 0; i < 2; i++)
#pragma unroll
      for (int j = 0; j < 4; j++) dots[i][j] = 0.f;
#pragma unroll 2
    for (int dd = 0; dd < 8; dd++) {
      const int d = adq * 8 + dd;
      u32 qw = *(const u32*)(lds + Q1B + ah * 2048 + d * 64 +
                             ((apos * 4) ^ (((d ^ ah) & 7) << 3)));
      uint2 kw = *(const uint2*)(lds + ah * 4096 + d * 128 +
                                 ((apos * 8) ^ (((d ^ ah) & 7) << 4)));
      float q[2] = { bflo(qw), bfhi(qw) };
      float k[4] = { bflo(kw.x), bfhi(kw.x), bflo(kw.y), bfhi(kw.y) };
#pragma unroll
      for (int i = 0; i < 2; i++)
#pragma unroll
        for (int j = 0; j < 4; j++) dots[i][j] += q[i] * k[j];
    }
#pragma unroll
    for (int i = 0; i < 2; i++)
#pragma unroll
      for (int j = 0; j < 4; j++) {
        float s = dots[i][j];
        s += __shfl_xor(s, 1);
        s += __shfl_xor(s, 2);
        dots[i][j] = s + maskv<1>(i, j);
      }
    if (adq == 0) {
#pragma unroll
      for (int i = 0; i < 2; i++) {
        const float mx = fmaxf(fmaxf(dots[i][0], dots[i][1]), fmaxf(dots[i][2], dots[i][3]));
        const float e0_ = __expf(dots[i][0] - mx), e1_ = __expf(dots[i][1] - mx);
        const float e2_ = __expf(dots[i][2] - mx), e3_ = __expf(dots[i][3] - mx);
        const float inv = 1.f / (e0_ + e1_ + e2_ + e3_);
        float4 pv_ = { e0_ * inv, e1_ * inv, e2_ * inv, e3_ * inv };
        *(float4*)(lds + P1B + ((apos * 8 + ah) * 2 + i) * 16) = pv_;
      }
    }
  }
  __syncthreads();   // p1 visible; Q1/K1 reads done -> 0-32K dead
  phase_fence();

  // ---- PV1 fused with attnout1 write (hi@0-16K, lo@16-32K; p1 @32-36K) ----
  {
    const int c = wave * 32 + cl;
#pragma unroll
    for (int gq = 0; gq < 4; gq++) {
      const int posA = 2 * gq + rh5;
#pragma unroll
      for (int i = 0; i < 2; i++) {
        float4 pa = *(const float4*)(lds + P1B + ((posA * 8 + wave) * 2 + i) * 16);
        const float o0 = pa.x * av0[4 * gq] + pa.y * av0[4 * gq + 1] +
                         pa.z * av0[4 * gq + 2] + pa.w * av0[4 * gq + 3];
        const int r0 = posA * 2 + i;
        const u32 h0 = cvt_pk(o0, o0);
        const int bo0 = (r0 * 512 + c * 2) ^ ((r0 & 15) << 4);
        *(u16*)(lds + bo0) = (u16)h0;
        *(u16*)(lds + AO1LB + bo0) = (u16)cvt_pk(o0 - bflo(h0), 0.f);
        float4 pb = *(const float4*)(lds + P1B + (((posA + 8) * 8 + wave) * 2 + i) * 16);
        const float o1 = pb.x * av1[4 * gq] + pb.y * av1[4 * gq + 1] +
                         pb.z * av1[4 * gq + 2] + pb.w * av1[4 * gq + 3];
        const int r1 = (posA + 8) * 2 + i;
        const u32 h1 = cvt_pk(o1, o1);
        const int bo1 = (r1 * 512 + c * 2) ^ ((r1 & 15) << 4);
        *(u16*)(lds + bo1) = (u16)h1;
        *(u16*)(lds + AO1LB + bo1) = (u16)cvt_pk(o1 - bflo(h1), 0.f);
      }
    }
  }
  __syncthreads();   // attnout1 visible; p1 reads done
  phase_fence();

  // ---- GEMM2 (3-pass) + epilogue ----
  {
    f32x16 acc2;
#pragma unroll
    for (int i = 0; i < 16; i++) acc2[i] = 0.f;
#pragma unroll 2
    for (int ks = 0; ks < 16; ks++) {
      const int k0 = ks * 16 + kgrp;
      const int bo = (cl * 512 + k0 * 2) ^ ((cl & 15) << 4);
      bf16x8 ahf = *(const bf16x8*)(lds + bo);
      bf16x8 alf = *(const bf16x8*)(lds + AO1LB + bo);
      bf16x8 bh = *(const bf16x8*)(wo1_hi + FRAG(wave, ks));
      bf16x8 bl = *(const bf16x8*)(wo1_lo + FRAG(wave, ks));
      __builtin_amdgcn_s_setprio(1);
      acc2 = __builtin_amdgcn_mfma_f32_32x32x16_bf16(ahf, bh, acc2, 0, 0, 0);
      acc2 = __builtin_amdgcn_mfma_f32_32x32x16_bf16(ahf, bl, acc2, 0, 0, 0);
      acc2 = __builtin_amdgcn_mfma_f32_32x32x16_bf16(alf, bh, acc2, 0, 0, 0);
      __builtin_amdgcn_s_setprio(0);
    }
    const int c = wave * 32 + cl;
    const float bc = bout1[c];
    const size_t TOT = (size_t)NB * NP * DIM;
#pragma unroll
    for (int i = 0; i < 16; i++) {
      const int r = (i & 3) + ((i >> 2) << 3) + 4 * rh5;
      const int pos = pos0 + (r >> 1);
      const float v = acc2[i] + bc;
      if ((r & 1) == 0) outp[((size_t)b * NP + pos) * DIM + c] = v;
      else              outp[TOT + ((size_t)b * NP + pos) * DIM + c] = v;
    }
  }
}

extern "C" void kernel_launch(void* const* d_in, const int* in_sizes, int n_in,
                              void* d_out, int out_size, void* d_ws, size_t ws_size,
                              hipStream_t stream) {
  const float* x     = (const float*)d_in[0];
  const float* y     = (const float*)d_in[1];
  const float* wqkv0 = (const float*)d_in[2];
  const float* wout0 = (const float*)d_in[3];
  const float* bout0 = (const float*)d_in[4];
  const float* wqkv1 = (const float*)d_in[5];
  const float* wout1 = (const float*)d_in[6];
  const float* bout1 = (const float*)d_in[7];

  float* part = (float*)d_ws;                        // 16*98*256
  float* Wc   = part + (size_t)16 * 98 * DIM;        // 768*256
  float* bq   = Wc + (size_t)768 * 256;              // 768
  float* qkvg = bq + 768;                            // 8*2*768
  u16* w = (u16*)(qkvg + (size_t)8 * 2 * 768);
  u16* wq0_hi = w; w += (size_t)768 * 256;
  u16* wc_hi  = w; w += (size_t)768 * 256;
  u16* wc_lo  = w; w += (size_t)768 * 256;
  u16* wo1_hi = w; w += (size_t)256 * 256;
  u16* wo1_lo = w; w += (size_t)256 * 256;

  prep1<<<dim3(2467), dim3(256), 0, stream>>>(
      x, y, part, wqkv0, wq0_hi, wout1, wo1_hi, wo1_lo,
      wqkv1, wout0, Wc, bout0, bq);
  prep2<<<dim3(112), dim3(256), 0, stream>>>(part, wqkv0, qkvg, Wc, wc_hi, wc_lo);

  fused_kernel<<<dim3(NP / PTILE, NB), dim3(512), LDS_SZ, stream>>>(
      x, y, qkvg, (float*)d_out,
      wq0_hi, wc_hi, wc_lo, wo1_hi, wo1_lo, bq, bout1);
}